// Round 4
// baseline (361.756 us; speedup 1.0000x reference)
//
#include <hip/hip_runtime.h>
#include <math.h>

#define BB 8
#define HH 512
#define WW 1024
#define HW (HH * WW)          // 524288 = 2^19
#define NPIX (BB * HW)        // 4194304
#define NSEG 16               // segments 1..16 (0 skipped)
#define SUPPRESS 0.1f

#define NREPM 16              // K_M replicas
#define RSTRIDEM 225          // odd word stride -> replicas shift banks
#define NREP2 16              // pass2 replicas
#define RSTRIDE2 17

// ws layout (bytes):
//   moments4 : double[4][8][16][14] @ 0      (57344)   4-way spread partials
//   res4     : double[4][8][16]     @ 57344  (4096)
//   scal64   : double[64][4]        @ 61440  (2048)    [dx,dy,Sb,Sbf] partials
//   maxfg64  : unsigned[64]         @ 63488  (256)
//   params   : float[128*6]         @ 63744  (3072)
//   valid    : int[128]             @ 66816  (512)
// total 67328 -> memset 67584

// ---------------- K_M: segment moments only ----------------
__global__ __launch_bounds__(256) void moments_kernel(
    const float* __restrict__ flow,
    const int*   __restrict__ masks,
    double* __restrict__ moments4)    // [4][8*16*14]
{
    __shared__ float binsR[NREPM * RSTRIDEM];
    const int tid = threadIdx.x;
    for (int t = tid; t < NREPM * RSTRIDEM; t += 256) binsR[t] = 0.f;
    __syncthreads();

    const long long base = (long long)blockIdx.x * 2048;
    const int b   = (int)(base >> 19);
    const int hwb = (int)(base & (HW - 1));
    const float* fu = flow + (long long)b * (2LL * HW);
    const float* fv = fu + HW;
    const int*   mk = masks + (long long)b * HW;
    const int rep = (tid & (NREPM - 1)) * RSTRIDEM;

    #pragma unroll
    for (int it = 0; it < 2; ++it) {
        const int p = hwb + it * 1024 + tid * 4;
        const int4   m4 = *(const int4*)&mk[p];
        const float4 u4 = *(const float4*)&fu[p];
        const float4 v4 = *(const float4*)&fv[p];
        const float y = (float)((p & (HW - 1)) >> 10);
        const float x0 = (float)(tid * 4);
        const int   segs[4] = {m4.x, m4.y, m4.z, m4.w};
        const float us[4]   = {u4.x, u4.y, u4.z, u4.w};
        const float vs[4]   = {v4.x, v4.y, v4.z, v4.w};
        #pragma unroll
        for (int j = 0; j < 4; ++j) {
            const int segc = segs[j];
            if (segc == 0) continue;
            float* bp = &binsR[rep + (segc - 1) * 14];
            const float x = x0 + (float)j;
            const float u = us[j], v = vs[j];
            atomicAdd(&bp[0], 1.f);
            atomicAdd(&bp[1], x);
            atomicAdd(&bp[2], y);
            atomicAdd(&bp[3], x * x);
            atomicAdd(&bp[4], x * y);
            atomicAdd(&bp[5], y * y);
            atomicAdd(&bp[6], u);
            atomicAdd(&bp[7], v);
            atomicAdd(&bp[8], u * u);
            atomicAdd(&bp[9], v * v);
            atomicAdd(&bp[10], x * u);
            atomicAdd(&bp[11], y * u);
            atomicAdd(&bp[12], x * v);
            atomicAdd(&bp[13], y * v);
        }
    }
    __syncthreads();
    if (tid < NSEG * 14) {
        float s = 0.f;
        #pragma unroll
        for (int r = 0; r < NREPM; ++r) s += binsR[r * RSTRIDEM + tid];
        const int par = blockIdx.x & 3;
        atomicAdd(&moments4[par * (8 * 16 * 14) + b * (16 * 14) + tid], (double)s);
    }
}

// ---------------- K_A: boundary, sobel, smooth (no atom* hot path) ----------------
__global__ __launch_bounds__(256) void stencil_kernel(
    const float* __restrict__ flow,
    const int*   __restrict__ masks,
    const float* __restrict__ images,
    double* __restrict__ scal64,      // [64][4]
    unsigned* __restrict__ maxfg64)   // [64]
{
    __shared__ float         sm[4][1032];
    __shared__ unsigned char smask[4][1032];
    __shared__ float         su[3][1024];
    __shared__ float         sv[3][1024];
    __shared__ float         sg[3][1024];
    __shared__ float         wred[4][5];

    const int tid = threadIdx.x;
    const int lane = tid & 63;
    const long long base = (long long)blockIdx.x * 2048;
    const int b  = (int)(base >> 19);
    const int h0 = (int)((base & (HW - 1)) >> 10);

    const float* fu = flow + (long long)b * (2LL * HW);
    const float* fv = fu + HW;
    const int*   mk = masks + (long long)b * HW;
    const float* i0 = images + (long long)b * (3LL * HW);
    const float* i1 = i0 + HW;
    const float* i2 = i1 + HW;

    const int c4 = tid * 4;
    #pragma unroll
    for (int r = 0; r < 4; ++r) {
        const int gr = h0 - 1 + r;
        const int mr = gr < 0 ? 0 : (gr > HH - 1 ? HH - 1 : gr);
        const int4 mv = *(const int4*)&mk[mr * WW + c4];
        uchar4 mb;
        mb.x = (unsigned char)mv.x; mb.y = (unsigned char)mv.y;
        mb.z = (unsigned char)mv.z; mb.w = (unsigned char)mv.w;
        *(uchar4*)&smask[r][4 + c4] = mb;

        float4 u4 = make_float4(0.f, 0.f, 0.f, 0.f);
        float4 v4 = make_float4(0.f, 0.f, 0.f, 0.f);
        if (gr >= 0 && gr <= HH - 1) {
            u4 = *(const float4*)&fu[gr * WW + c4];
            v4 = *(const float4*)&fv[gr * WW + c4];
        }
        float4 m4;
        m4.x = sqrtf(u4.x * u4.x + v4.x * v4.x);
        m4.y = sqrtf(u4.y * u4.y + v4.y * v4.y);
        m4.z = sqrtf(u4.z * u4.z + v4.z * v4.z);
        m4.w = sqrtf(u4.w * u4.w + v4.w * v4.w);
        *(float4*)&sm[r][4 + c4] = m4;
        if (r >= 1) {
            *(float4*)&su[r - 1][c4] = u4;
            *(float4*)&sv[r - 1][c4] = v4;
        }
    }
    #pragma unroll
    for (int r = 0; r < 3; ++r) {
        const int gr = h0 + r;
        float4 g4 = make_float4(0.f, 0.f, 0.f, 0.f);
        if (gr <= HH - 1) {
            const float4 a  = *(const float4*)&i0[gr * WW + c4];
            const float4 bq = *(const float4*)&i1[gr * WW + c4];
            const float4 c  = *(const float4*)&i2[gr * WW + c4];
            g4.x = (a.x + bq.x + c.x) * (1.f / 3.f);
            g4.y = (a.y + bq.y + c.y) * (1.f / 3.f);
            g4.z = (a.z + bq.z + c.z) * (1.f / 3.f);
            g4.w = (a.w + bq.w + c.w) * (1.f / 3.f);
        }
        *(float4*)&sg[r][c4] = g4;
    }
    if (tid < 4) {
        const int gr = h0 - 1 + tid;
        const int mr = gr < 0 ? 0 : (gr > HH - 1 ? HH - 1 : gr);
        smask[tid][3]    = (unsigned char)mk[mr * WW + 0];
        smask[tid][1028] = (unsigned char)mk[mr * WW + WW - 1];
        sm[tid][3] = 0.f;
        sm[tid][1028] = 0.f;
    }
    __syncthreads();

    float a_dx = 0.f, a_dy = 0.f, a_sb = 0.f, a_sbf = 0.f, mfg = 0.f;

    #pragma unroll
    for (int it = 0; it < 8; ++it) {
        const int idx = it * 256 + tid;
        const int lr = idx >> 10;
        const int w  = idx & 1023;
        const int h  = h0 + lr;
        const int cc = 4 + w;

        const int segc = smask[lr + 1][cc];
        int bnd = (smask[lr][cc - 1] != segc) | (smask[lr][cc] != segc) |
                  (smask[lr][cc + 1] != segc) |
                  (smask[lr + 1][cc - 1] != segc) | (smask[lr + 1][cc + 1] != segc) |
                  (smask[lr + 2][cc - 1] != segc) | (smask[lr + 2][cc] != segc) |
                  (smask[lr + 2][cc + 1] != segc);

        const float t00 = sm[lr][cc - 1],     t01 = sm[lr][cc],     t02 = sm[lr][cc + 1];
        const float t10 = sm[lr + 1][cc - 1],                       t12 = sm[lr + 1][cc + 1];
        const float t20 = sm[lr + 2][cc - 1], t21 = sm[lr + 2][cc], t22 = sm[lr + 2][cc + 1];
        const float fgx = (t02 - t00) + 2.f * (t12 - t10) + (t22 - t20);
        const float fgy = (t20 + 2.f * t21 + t22) - (t00 + 2.f * t01 + t02);
        const float fgraw = fabsf(fgx) + fabsf(fgy);
        mfg = fmaxf(mfg, fgraw);
        if (bnd) { a_sb += 1.f; a_sbf += fgraw; }

        const float u = su[lr][w], v = sv[lr][w];
        const float g0 = sg[lr][w];
        if (w < WW - 1) {
            const float wgt = expf(-fabsf(sg[lr][w + 1] - g0) * 10.f) * (bnd ? SUPPRESS : 1.f);
            a_dx += (fabsf(su[lr][w + 1] - u) + fabsf(sv[lr][w + 1] - v)) * wgt;
        }
        if (h < HH - 1) {
            const float wgt = expf(-fabsf(sg[lr + 1][w] - g0) * 10.f) * (bnd ? SUPPRESS : 1.f);
            a_dy += (fabsf(su[lr + 1][w] - u) + fabsf(sv[lr + 1][w] - v)) * wgt;
        }
    }

    for (int off = 32; off > 0; off >>= 1) {
        a_dx += __shfl_down(a_dx, off);
        a_dy += __shfl_down(a_dy, off);
        a_sb += __shfl_down(a_sb, off);
        a_sbf += __shfl_down(a_sbf, off);
        mfg = fmaxf(mfg, __shfl_down(mfg, off));
    }
    if (lane == 0) {
        const int wv = tid >> 6;
        wred[wv][0] = a_dx; wred[wv][1] = a_dy; wred[wv][2] = a_sb;
        wred[wv][3] = a_sbf; wred[wv][4] = mfg;
    }
    __syncthreads();
    if (tid == 0) {
        float dx = 0.f, dy = 0.f, sb = 0.f, sbf = 0.f, mf = 0.f;
        for (int i = 0; i < 4; ++i) {
            dx += wred[i][0]; dy += wred[i][1]; sb += wred[i][2];
            sbf += wred[i][3]; mf = fmaxf(mf, wred[i][4]);
        }
        const int sl = blockIdx.x & 63;
        atomicAdd(&scal64[sl * 4 + 0], (double)dx);
        atomicAdd(&scal64[sl * 4 + 1], (double)dy);
        atomicAdd(&scal64[sl * 4 + 2], (double)sb);
        atomicAdd(&scal64[sl * 4 + 3], (double)sbf);
        atomicMax(&maxfg64[sl], __float_as_uint(mf));
    }
}

// ---------------- solve: sum partials, 3x3 normal equations + variance ----------------
__global__ __launch_bounds__(128) void solve_kernel(
    const double* __restrict__ moments4,
    float* __restrict__ params,   // [128][6]
    int* __restrict__ valid,      // [128]
    float* __restrict__ out)
{
    const int i = threadIdx.x;    // (b, seg-1)
    double m[14];
    #pragma unroll
    for (int k = 0; k < 14; ++k) {
        double s = 0.0;
        #pragma unroll
        for (int par = 0; par < 4; ++par) s += moments4[par * 1792 + i * 14 + k];
        m[k] = s;
    }
    const double n = m[0];
    const int vh = (n >= 100.0) ? 1 : 0;
    float p[6] = {0.f, 0.f, 0.f, 0.f, 0.f, 0.f};
    if (vh) {
        double A[3][3] = {{m[3], m[4], m[1]},
                          {m[4], m[5], m[2]},
                          {m[1], m[2], n}};
        double Bm[3][2] = {{m[10], m[12]},
                           {m[11], m[13]},
                           {m[6],  m[7]}};
        for (int k = 0; k < 3; ++k) {
            int piv = k; double mx = fabs(A[k][k]);
            for (int r = k + 1; r < 3; ++r) {
                double a = fabs(A[r][k]);
                if (a > mx) { mx = a; piv = r; }
            }
            if (piv != k) {
                for (int c = 0; c < 3; ++c) { double t = A[k][c]; A[k][c] = A[piv][c]; A[piv][c] = t; }
                for (int c = 0; c < 2; ++c) { double t = Bm[k][c]; Bm[k][c] = Bm[piv][c]; Bm[piv][c] = t; }
            }
            const double inv = 1.0 / A[k][k];
            for (int r = k + 1; r < 3; ++r) {
                const double f = A[r][k] * inv;
                for (int c = k; c < 3; ++c) A[r][c] -= f * A[k][c];
                Bm[r][0] -= f * Bm[k][0];
                Bm[r][1] -= f * Bm[k][1];
            }
        }
        double X[3][2];
        for (int c = 0; c < 2; ++c) {
            X[2][c] = Bm[2][c] / A[2][2];
            X[1][c] = (Bm[1][c] - A[1][2] * X[2][c]) / A[1][1];
            X[0][c] = (Bm[0][c] - A[0][1] * X[1][c] - A[0][2] * X[2][c]) / A[0][0];
        }
        p[0] = (float)X[0][0]; p[1] = (float)X[1][0]; p[2] = (float)X[2][0];
        p[3] = (float)X[0][1]; p[4] = (float)X[1][1]; p[5] = (float)X[2][1];
    }
    valid[i] = vh;
    for (int c = 0; c < 6; ++c) params[i * 6 + c] = p[c];

    const int vv = (n >= 50.0) ? 1 : 0;
    double var = 0.0;
    if (vv) {
        const double ns = (n > 2.0) ? n : 2.0;
        const double var_u = (m[8] - m[6] * m[6] / ns) / (ns - 1.0);
        const double var_v = (m[9] - m[7] * m[7] / ns) / (ns - 1.0);
        var = var_u + var_v;
    }
    __shared__ double svar[128];
    __shared__ int scnt[128];
    svar[i] = var; scnt[i] = vv;
    __syncthreads();
    for (int s = 64; s > 0; s >>= 1) {
        if (i < s) { svar[i] += svar[i + s]; scnt[i] += scnt[i + s]; }
        __syncthreads();
    }
    if (i == 0) out[2] = (float)(svar[0] / (double)(scnt[0] > 1 ? scnt[0] : 1));
}

// ---------------- pass 2: per-pixel affine-fit residuals ----------------
__global__ __launch_bounds__(256) void pass2_kernel(
    const float* __restrict__ flow,
    const int*   __restrict__ masks,
    const float* __restrict__ params,
    const int*   __restrict__ valid,
    double* __restrict__ res4)        // [4][8][16]
{
    __shared__ float rbinsR[NREP2 * RSTRIDE2];
    __shared__ float sp[NSEG * 6];
    __shared__ int   sv_[NSEG];

    const long long base = (long long)blockIdx.x * 4096;
    const int b      = (int)(base >> 19);
    const int hwbase = (int)(base & (HW - 1));

    for (int t = threadIdx.x; t < NREP2 * RSTRIDE2; t += 256) rbinsR[t] = 0.f;
    if (threadIdx.x < NSEG) sv_[threadIdx.x] = valid[b * NSEG + threadIdx.x];
    if (threadIdx.x < NSEG * 6) sp[threadIdx.x] = params[b * NSEG * 6 + threadIdx.x];
    __syncthreads();

    const float* fu = flow + (long long)b * (2LL * HW);
    const float* fv = fu + HW;
    const int*   mk = masks + (long long)b * HW;
    const int repbase = (threadIdx.x & (NREP2 - 1)) * RSTRIDE2;

    #pragma unroll
    for (int it = 0; it < 4; ++it) {
        const int i4 = hwbase + it * 1024 + threadIdx.x * 4;
        const int4   m4 = *(const int4*)&mk[i4];
        const float4 u4 = *(const float4*)&fu[i4];
        const float4 v4 = *(const float4*)&fv[i4];
        const int segs[4] = {m4.x, m4.y, m4.z, m4.w};
        const float us[4] = {u4.x, u4.y, u4.z, u4.w};
        const float vs[4] = {v4.x, v4.y, v4.z, v4.w};
        #pragma unroll
        for (int j = 0; j < 4; ++j) {
            const int segc = segs[j];
            if (segc == 0) continue;
            if (!sv_[segc - 1]) continue;
            const float* pf = &sp[(segc - 1) * 6];
            const int hw = i4 + j;
            const float x = (float)(hw & 1023), y = (float)(hw >> 10);
            const float du = us[j] - (x * pf[0] + y * pf[1] + pf[2]);
            const float dv = vs[j] - (x * pf[3] + y * pf[4] + pf[5]);
            atomicAdd(&rbinsR[repbase + (segc - 1)], sqrtf(du * du + dv * dv));
        }
    }
    __syncthreads();
    if (threadIdx.x < NSEG) {
        float s = 0.f;
        #pragma unroll
        for (int r = 0; r < NREP2; ++r) s += rbinsR[r * RSTRIDE2 + threadIdx.x];
        const int par = blockIdx.x & 3;
        atomicAdd(&res4[par * 128 + b * 16 + threadIdx.x], (double)s);
    }
}

// ---------------- finalize: homog, sharp, smooth ----------------
__global__ __launch_bounds__(128) void final_kernel(
    const double* __restrict__ moments4,
    const double* __restrict__ res4,
    const int*    __restrict__ valid,
    const double* __restrict__ scal64,
    const unsigned* __restrict__ maxfg64,
    float* __restrict__ out)
{
    const int i = threadIdx.x;
    double n = 0.0, rs = 0.0;
    #pragma unroll
    for (int par = 0; par < 4; ++par) {
        n  += moments4[par * 1792 + i * 14];
        rs += res4[par * 128 + i];
    }
    const int vh = valid[i];
    const double rm = vh ? rs / (n > 1.0 ? n : 1.0) : 0.0;
    __shared__ double sr[128];
    __shared__ int sc[128];
    sr[i] = rm; sc[i] = vh;
    __syncthreads();
    for (int s = 64; s > 0; s >>= 1) {
        if (i < s) { sr[i] += sr[i + s]; sc[i] += sc[i + s]; }
        __syncthreads();
    }
    if (i == 0) {
        out[0] = (float)(sr[0] / (double)(sc[0] > 1 ? sc[0] : 1));
        double dx = 0.0, dy = 0.0, sb = 0.0, sbf = 0.0;
        float mf = 0.f;
        for (int k = 0; k < 64; ++k) {
            dx += scal64[k * 4 + 0]; dy += scal64[k * 4 + 1];
            sb += scal64[k * 4 + 2]; sbf += scal64[k * 4 + 3];
            mf = fmaxf(mf, __uint_as_float(maxfg64[k]));
        }
        const double maxfg = (double)mf;
        const double maxb = (sb > 0.0) ? 1.0 : 0.0;
        out[1] = (float)((sb - sbf / (maxfg + 1e-6)) / (maxb + 1e-6) / (double)NPIX);
        const double smooth = dx / (double)(2LL * BB * HH * (WW - 1)) +
                              dy / (double)(2LL * BB * (HH - 1) * WW);
        out[3] = (float)smooth;
    }
}

extern "C" void kernel_launch(void* const* d_in, const int* in_sizes, int n_in,
                              void* d_out, int out_size, void* d_ws, size_t ws_size,
                              hipStream_t stream)
{
    const float* flow   = (const float*)d_in[0];
    const int*   masks  = (const int*)d_in[1];
    const float* images = (const float*)d_in[2];
    float* out = (float*)d_out;

    char* ws = (char*)d_ws;
    double*   moments4 = (double*)(ws);             // 0     .. 57344
    double*   res4     = (double*)(ws + 57344);     // 57344 .. 61440
    double*   scal64   = (double*)(ws + 61440);     // 61440 .. 63488
    unsigned* maxfg64  = (unsigned*)(ws + 63488);   // 63488 .. 63744
    float*    params   = (float*)(ws + 63744);      // 63744 .. 66816
    int*      valid    = (int*)(ws + 66816);        // 66816 .. 67328

    hipMemsetAsync(d_ws, 0, 67584, stream);

    moments_kernel<<<dim3(NPIX / 2048), dim3(256), 0, stream>>>(flow, masks, moments4);
    stencil_kernel<<<dim3(NPIX / 2048), dim3(256), 0, stream>>>(
        flow, masks, images, scal64, maxfg64);
    solve_kernel<<<dim3(1), dim3(128), 0, stream>>>(moments4, params, valid, out);
    pass2_kernel<<<dim3(NPIX / 4096), dim3(256), 0, stream>>>(
        flow, masks, params, valid, res4);
    final_kernel<<<dim3(1), dim3(128), 0, stream>>>(
        moments4, res4, valid, scal64, maxfg64, out);
}

// Round 5
// 237.192 us; speedup vs baseline: 1.5252x; 1.5252x over previous
//
#include <hip/hip_runtime.h>
#include <math.h>

#define BB 8
#define HH 512
#define WW 1024
#define HW (HH * WW)          // 524288 = 2^19
#define NPIX (BB * HW)        // 4194304
#define NSEG 16               // segments 1..16 (0 skipped)
#define SUPPRESS 0.1f

// ws layout (bytes):
//   moments4 : double[4][8][16][14] @ 0      (57344)   4-way spread partials
//   res4     : double[4][8][16]     @ 57344  (4096)
//   scal64   : double[64][4]        @ 61440  (2048)    [dx,dy,Sb,Sbf] partials
//   maxfg64  : unsigned[64]         @ 63488  (256)
//   params   : float[128*6]         @ 63744  (3072)
//   valid    : int[128]             @ 66816  (512)

// ---------------- K_M: segment moments via delta-predicated register accumulation ----------------
// Block = 256 thr (4 waves), tile = 2048 px. Each wave scans the WHOLE tile and
// accumulates its feature subset for all 16 segments in registers. No atomics
// in the hot loop (gfx950 LDS atomic RMW measured ~3 cyc/lane -> 282 us; VALU
// predication is ~10x cheaper).
template <int W>
__device__ __forceinline__ void moments_body(
    const float* __restrict__ fu, const float* __restrict__ fv,
    const int* __restrict__ mk, int hwb, int h0, int lane, int b, int par,
    double* __restrict__ moments4)
{
    constexpr int NK = (W < 2) ? 4 : 3;
    constexpr int FBASE = (W == 0) ? 0 : (W == 1) ? 4 : (W == 2) ? 8 : 11;
    float acc[16][NK];
    #pragma unroll
    for (int s = 0; s < 16; ++s)
        #pragma unroll
        for (int k = 0; k < NK; ++k) acc[s][k] = 0.f;

    #pragma unroll 1
    for (int it = 0; it < 8; ++it) {
        const int t = it * 256 + lane * 4;
        const int4   m4 = *(const int4*)&mk[hwb + t];
        const float4 u4 = *(const float4*)&fu[hwb + t];
        const float4 v4 = *(const float4*)&fv[hwb + t];
        const int   segs[4] = {m4.x, m4.y, m4.z, m4.w};
        const float us[4]   = {u4.x, u4.y, u4.z, u4.w};
        const float vs[4]   = {v4.x, v4.y, v4.z, v4.w};
        #pragma unroll
        for (int j = 0; j < 4; ++j) {
            const float x = (float)((t + j) & 1023);
            const float y = (float)(h0 + ((t + j) >> 10));
            const float u = us[j], v = vs[j];
            float f[NK];
            if constexpr (W == 0)      { f[0] = 1.f;   f[1] = x;     f[2] = y;     f[3] = x * x; }
            else if constexpr (W == 1) { f[0] = x * y; f[1] = y * y; f[2] = u;     f[3] = v; }
            else if constexpr (W == 2) { f[0] = u * u; f[1] = v * v; f[2] = x * u; }
            else                       { f[0] = y * u; f[1] = x * v; f[2] = y * v; }
            const int seg = segs[j];
            #pragma unroll
            for (int s = 0; s < 16; ++s) {
                const float d = (seg == s + 1) ? 1.f : 0.f;
                #pragma unroll
                for (int k = 0; k < NK; ++k) acc[s][k] = fmaf(d, f[k], acc[s][k]);
            }
        }
    }

    #pragma unroll
    for (int s = 0; s < 16; ++s) {
        #pragma unroll
        for (int k = 0; k < NK; ++k) {
            float vsum = acc[s][k];
            #pragma unroll
            for (int off = 32; off > 0; off >>= 1) vsum += __shfl_down(vsum, off);
            if (lane == 0)
                atomicAdd(&moments4[par * 1792 + b * 224 + s * 14 + FBASE + k],
                          (double)vsum);
        }
    }
}

__global__ __launch_bounds__(256, 4) void moments_kernel(
    const float* __restrict__ flow,
    const int*   __restrict__ masks,
    double* __restrict__ moments4)    // [4][8*16*14]
{
    const int tid  = threadIdx.x;
    const int lane = tid & 63;
    const int w    = tid >> 6;
    const long long base = (long long)blockIdx.x * 2048;
    const int b   = (int)(base >> 19);
    const int hwb = (int)(base & (HW - 1));
    const int h0  = hwb >> 10;
    const int par = blockIdx.x & 3;

    const float* fu = flow + (long long)b * (2LL * HW);
    const float* fv = fu + HW;
    const int*   mk = masks + (long long)b * HW;

    if (w == 0)      moments_body<0>(fu, fv, mk, hwb, h0, lane, b, par, moments4);
    else if (w == 1) moments_body<1>(fu, fv, mk, hwb, h0, lane, b, par, moments4);
    else if (w == 2) moments_body<2>(fu, fv, mk, hwb, h0, lane, b, par, moments4);
    else             moments_body<3>(fu, fv, mk, hwb, h0, lane, b, par, moments4);
}

// ---------------- K_A: boundary, sobel, smooth (unchanged, validated) ----------------
__global__ __launch_bounds__(256) void stencil_kernel(
    const float* __restrict__ flow,
    const int*   __restrict__ masks,
    const float* __restrict__ images,
    double* __restrict__ scal64,      // [64][4]
    unsigned* __restrict__ maxfg64)   // [64]
{
    __shared__ float         sm[4][1032];
    __shared__ unsigned char smask[4][1032];
    __shared__ float         su[3][1024];
    __shared__ float         sv[3][1024];
    __shared__ float         sg[3][1024];
    __shared__ float         wred[4][5];

    const int tid = threadIdx.x;
    const int lane = tid & 63;
    const long long base = (long long)blockIdx.x * 2048;
    const int b  = (int)(base >> 19);
    const int h0 = (int)((base & (HW - 1)) >> 10);

    const float* fu = flow + (long long)b * (2LL * HW);
    const float* fv = fu + HW;
    const int*   mk = masks + (long long)b * HW;
    const float* i0 = images + (long long)b * (3LL * HW);
    const float* i1 = i0 + HW;
    const float* i2 = i1 + HW;

    const int c4 = tid * 4;
    #pragma unroll
    for (int r = 0; r < 4; ++r) {
        const int gr = h0 - 1 + r;
        const int mr = gr < 0 ? 0 : (gr > HH - 1 ? HH - 1 : gr);
        const int4 mv = *(const int4*)&mk[mr * WW + c4];
        uchar4 mb;
        mb.x = (unsigned char)mv.x; mb.y = (unsigned char)mv.y;
        mb.z = (unsigned char)mv.z; mb.w = (unsigned char)mv.w;
        *(uchar4*)&smask[r][4 + c4] = mb;

        float4 u4 = make_float4(0.f, 0.f, 0.f, 0.f);
        float4 v4 = make_float4(0.f, 0.f, 0.f, 0.f);
        if (gr >= 0 && gr <= HH - 1) {
            u4 = *(const float4*)&fu[gr * WW + c4];
            v4 = *(const float4*)&fv[gr * WW + c4];
        }
        float4 m4;
        m4.x = sqrtf(u4.x * u4.x + v4.x * v4.x);
        m4.y = sqrtf(u4.y * u4.y + v4.y * v4.y);
        m4.z = sqrtf(u4.z * u4.z + v4.z * v4.z);
        m4.w = sqrtf(u4.w * u4.w + v4.w * v4.w);
        *(float4*)&sm[r][4 + c4] = m4;
        if (r >= 1) {
            *(float4*)&su[r - 1][c4] = u4;
            *(float4*)&sv[r - 1][c4] = v4;
        }
    }
    #pragma unroll
    for (int r = 0; r < 3; ++r) {
        const int gr = h0 + r;
        float4 g4 = make_float4(0.f, 0.f, 0.f, 0.f);
        if (gr <= HH - 1) {
            const float4 a  = *(const float4*)&i0[gr * WW + c4];
            const float4 bq = *(const float4*)&i1[gr * WW + c4];
            const float4 c  = *(const float4*)&i2[gr * WW + c4];
            g4.x = (a.x + bq.x + c.x) * (1.f / 3.f);
            g4.y = (a.y + bq.y + c.y) * (1.f / 3.f);
            g4.z = (a.z + bq.z + c.z) * (1.f / 3.f);
            g4.w = (a.w + bq.w + c.w) * (1.f / 3.f);
        }
        *(float4*)&sg[r][c4] = g4;
    }
    if (tid < 4) {
        const int gr = h0 - 1 + tid;
        const int mr = gr < 0 ? 0 : (gr > HH - 1 ? HH - 1 : gr);
        smask[tid][3]    = (unsigned char)mk[mr * WW + 0];
        smask[tid][1028] = (unsigned char)mk[mr * WW + WW - 1];
        sm[tid][3] = 0.f;
        sm[tid][1028] = 0.f;
    }
    __syncthreads();

    float a_dx = 0.f, a_dy = 0.f, a_sb = 0.f, a_sbf = 0.f, mfg = 0.f;

    #pragma unroll
    for (int it = 0; it < 8; ++it) {
        const int idx = it * 256 + tid;
        const int lr = idx >> 10;
        const int w  = idx & 1023;
        const int h  = h0 + lr;
        const int cc = 4 + w;

        const int segc = smask[lr + 1][cc];
        int bnd = (smask[lr][cc - 1] != segc) | (smask[lr][cc] != segc) |
                  (smask[lr][cc + 1] != segc) |
                  (smask[lr + 1][cc - 1] != segc) | (smask[lr + 1][cc + 1] != segc) |
                  (smask[lr + 2][cc - 1] != segc) | (smask[lr + 2][cc] != segc) |
                  (smask[lr + 2][cc + 1] != segc);

        const float t00 = sm[lr][cc - 1],     t01 = sm[lr][cc],     t02 = sm[lr][cc + 1];
        const float t10 = sm[lr + 1][cc - 1],                       t12 = sm[lr + 1][cc + 1];
        const float t20 = sm[lr + 2][cc - 1], t21 = sm[lr + 2][cc], t22 = sm[lr + 2][cc + 1];
        const float fgx = (t02 - t00) + 2.f * (t12 - t10) + (t22 - t20);
        const float fgy = (t20 + 2.f * t21 + t22) - (t00 + 2.f * t01 + t02);
        const float fgraw = fabsf(fgx) + fabsf(fgy);
        mfg = fmaxf(mfg, fgraw);
        if (bnd) { a_sb += 1.f; a_sbf += fgraw; }

        const float u = su[lr][w], v = sv[lr][w];
        const float g0 = sg[lr][w];
        if (w < WW - 1) {
            const float wgt = expf(-fabsf(sg[lr][w + 1] - g0) * 10.f) * (bnd ? SUPPRESS : 1.f);
            a_dx += (fabsf(su[lr][w + 1] - u) + fabsf(sv[lr][w + 1] - v)) * wgt;
        }
        if (h < HH - 1) {
            const float wgt = expf(-fabsf(sg[lr + 1][w] - g0) * 10.f) * (bnd ? SUPPRESS : 1.f);
            a_dy += (fabsf(su[lr + 1][w] - u) + fabsf(sv[lr + 1][w] - v)) * wgt;
        }
    }

    for (int off = 32; off > 0; off >>= 1) {
        a_dx += __shfl_down(a_dx, off);
        a_dy += __shfl_down(a_dy, off);
        a_sb += __shfl_down(a_sb, off);
        a_sbf += __shfl_down(a_sbf, off);
        mfg = fmaxf(mfg, __shfl_down(mfg, off));
    }
    if (lane == 0) {
        const int wv = tid >> 6;
        wred[wv][0] = a_dx; wred[wv][1] = a_dy; wred[wv][2] = a_sb;
        wred[wv][3] = a_sbf; wred[wv][4] = mfg;
    }
    __syncthreads();
    if (tid == 0) {
        float dx = 0.f, dy = 0.f, sb = 0.f, sbf = 0.f, mf = 0.f;
        for (int i = 0; i < 4; ++i) {
            dx += wred[i][0]; dy += wred[i][1]; sb += wred[i][2];
            sbf += wred[i][3]; mf = fmaxf(mf, wred[i][4]);
        }
        const int sl = blockIdx.x & 63;
        atomicAdd(&scal64[sl * 4 + 0], (double)dx);
        atomicAdd(&scal64[sl * 4 + 1], (double)dy);
        atomicAdd(&scal64[sl * 4 + 2], (double)sb);
        atomicAdd(&scal64[sl * 4 + 3], (double)sbf);
        atomicMax(&maxfg64[sl], __float_as_uint(mf));
    }
}

// ---------------- solve: sum partials, 3x3 normal equations + variance ----------------
__global__ __launch_bounds__(128) void solve_kernel(
    const double* __restrict__ moments4,
    float* __restrict__ params,   // [128][6]
    int* __restrict__ valid,      // [128]
    float* __restrict__ out)
{
    const int i = threadIdx.x;    // (b, seg-1)
    double m[14];
    #pragma unroll
    for (int k = 0; k < 14; ++k) {
        double s = 0.0;
        #pragma unroll
        for (int par = 0; par < 4; ++par) s += moments4[par * 1792 + i * 14 + k];
        m[k] = s;
    }
    const double n = m[0];
    const int vh = (n >= 100.0) ? 1 : 0;
    float p[6] = {0.f, 0.f, 0.f, 0.f, 0.f, 0.f};
    if (vh) {
        double A[3][3] = {{m[3], m[4], m[1]},
                          {m[4], m[5], m[2]},
                          {m[1], m[2], n}};
        double Bm[3][2] = {{m[10], m[12]},
                           {m[11], m[13]},
                           {m[6],  m[7]}};
        for (int k = 0; k < 3; ++k) {
            int piv = k; double mx = fabs(A[k][k]);
            for (int r = k + 1; r < 3; ++r) {
                double a = fabs(A[r][k]);
                if (a > mx) { mx = a; piv = r; }
            }
            if (piv != k) {
                for (int c = 0; c < 3; ++c) { double t = A[k][c]; A[k][c] = A[piv][c]; A[piv][c] = t; }
                for (int c = 0; c < 2; ++c) { double t = Bm[k][c]; Bm[k][c] = Bm[piv][c]; Bm[piv][c] = t; }
            }
            const double inv = 1.0 / A[k][k];
            for (int r = k + 1; r < 3; ++r) {
                const double f = A[r][k] * inv;
                for (int c = k; c < 3; ++c) A[r][c] -= f * A[k][c];
                Bm[r][0] -= f * Bm[k][0];
                Bm[r][1] -= f * Bm[k][1];
            }
        }
        double X[3][2];
        for (int c = 0; c < 2; ++c) {
            X[2][c] = Bm[2][c] / A[2][2];
            X[1][c] = (Bm[1][c] - A[1][2] * X[2][c]) / A[1][1];
            X[0][c] = (Bm[0][c] - A[0][1] * X[1][c] - A[0][2] * X[2][c]) / A[0][0];
        }
        p[0] = (float)X[0][0]; p[1] = (float)X[1][0]; p[2] = (float)X[2][0];
        p[3] = (float)X[0][1]; p[4] = (float)X[1][1]; p[5] = (float)X[2][1];
    }
    valid[i] = vh;
    for (int c = 0; c < 6; ++c) params[i * 6 + c] = p[c];

    const int vv = (n >= 50.0) ? 1 : 0;
    double var = 0.0;
    if (vv) {
        const double ns = (n > 2.0) ? n : 2.0;
        const double var_u = (m[8] - m[6] * m[6] / ns) / (ns - 1.0);
        const double var_v = (m[9] - m[7] * m[7] / ns) / (ns - 1.0);
        var = var_u + var_v;
    }
    __shared__ double svar[128];
    __shared__ int scnt[128];
    svar[i] = var; scnt[i] = vv;
    __syncthreads();
    for (int s = 64; s > 0; s >>= 1) {
        if (i < s) { svar[i] += svar[i + s]; scnt[i] += scnt[i + s]; }
        __syncthreads();
    }
    if (i == 0) out[2] = (float)(svar[0] / (double)(scnt[0] > 1 ? scnt[0] : 1));
}

// ---------------- pass 2: residuals via delta-predicated register accumulation ----------------
__global__ __launch_bounds__(256, 4) void pass2_kernel(
    const float* __restrict__ flow,
    const int*   __restrict__ masks,
    const float* __restrict__ params,
    double* __restrict__ res4)        // [4][8][16]
{
    __shared__ float sp[17 * 6];      // row 0 = zeros (background)

    const long long base = (long long)blockIdx.x * 4096;
    const int b      = (int)(base >> 19);
    const int hwbase = (int)(base & (HW - 1));
    const int tid    = threadIdx.x;
    const int lane   = tid & 63;

    if (tid < 6) sp[tid] = 0.f;
    if (tid < 96) sp[6 + tid] = params[b * 96 + tid];
    __syncthreads();

    const float* fu = flow + (long long)b * (2LL * HW);
    const float* fv = fu + HW;
    const int*   mk = masks + (long long)b * HW;

    float acc[16];
    #pragma unroll
    for (int s = 0; s < 16; ++s) acc[s] = 0.f;

    #pragma unroll 1
    for (int it = 0; it < 4; ++it) {
        const int i4 = hwbase + it * 1024 + tid * 4;
        const int4   m4 = *(const int4*)&mk[i4];
        const float4 u4 = *(const float4*)&fu[i4];
        const float4 v4 = *(const float4*)&fv[i4];
        const int segs[4] = {m4.x, m4.y, m4.z, m4.w};
        const float us[4] = {u4.x, u4.y, u4.z, u4.w};
        const float vs[4] = {v4.x, v4.y, v4.z, v4.w};
        #pragma unroll
        for (int j = 0; j < 4; ++j) {
            const int seg = segs[j];
            const float* pf = &sp[seg * 6];
            const int hw = i4 + j;
            const float x = (float)(hw & 1023), y = (float)((hw & (HW - 1)) >> 10);
            const float du = us[j] - (x * pf[0] + y * pf[1] + pf[2]);
            const float dv = vs[j] - (x * pf[3] + y * pf[4] + pf[5]);
            const float r = sqrtf(du * du + dv * dv);
            #pragma unroll
            for (int s = 0; s < 16; ++s)
                acc[s] += (seg == s + 1) ? r : 0.f;
        }
    }

    const int par = blockIdx.x & 3;
    #pragma unroll
    for (int s = 0; s < 16; ++s) {
        float vsum = acc[s];
        #pragma unroll
        for (int off = 32; off > 0; off >>= 1) vsum += __shfl_down(vsum, off);
        if (lane == 0)
            atomicAdd(&res4[par * 128 + b * 16 + s], (double)vsum);
    }
}

// ---------------- finalize: homog, sharp, smooth ----------------
__global__ __launch_bounds__(128) void final_kernel(
    const double* __restrict__ moments4,
    const double* __restrict__ res4,
    const int*    __restrict__ valid,
    const double* __restrict__ scal64,
    const unsigned* __restrict__ maxfg64,
    float* __restrict__ out)
{
    const int i = threadIdx.x;
    double n = 0.0, rs = 0.0;
    #pragma unroll
    for (int par = 0; par < 4; ++par) {
        n  += moments4[par * 1792 + i * 14];
        rs += res4[par * 128 + i];
    }
    const int vh = valid[i];
    const double rm = vh ? rs / (n > 1.0 ? n : 1.0) : 0.0;
    __shared__ double sr[128];
    __shared__ int sc[128];
    sr[i] = rm; sc[i] = vh;
    __syncthreads();
    for (int s = 64; s > 0; s >>= 1) {
        if (i < s) { sr[i] += sr[i + s]; sc[i] += sc[i + s]; }
        __syncthreads();
    }
    if (i == 0) {
        out[0] = (float)(sr[0] / (double)(sc[0] > 1 ? sc[0] : 1));
        double dx = 0.0, dy = 0.0, sb = 0.0, sbf = 0.0;
        float mf = 0.f;
        for (int k = 0; k < 64; ++k) {
            dx += scal64[k * 4 + 0]; dy += scal64[k * 4 + 1];
            sb += scal64[k * 4 + 2]; sbf += scal64[k * 4 + 3];
            mf = fmaxf(mf, __uint_as_float(maxfg64[k]));
        }
        const double maxfg = (double)mf;
        const double maxb = (sb > 0.0) ? 1.0 : 0.0;
        out[1] = (float)((sb - sbf / (maxfg + 1e-6)) / (maxb + 1e-6) / (double)NPIX);
        const double smooth = dx / (double)(2LL * BB * HH * (WW - 1)) +
                              dy / (double)(2LL * BB * (HH - 1) * WW);
        out[3] = (float)smooth;
    }
}

extern "C" void kernel_launch(void* const* d_in, const int* in_sizes, int n_in,
                              void* d_out, int out_size, void* d_ws, size_t ws_size,
                              hipStream_t stream)
{
    const float* flow   = (const float*)d_in[0];
    const int*   masks  = (const int*)d_in[1];
    const float* images = (const float*)d_in[2];
    float* out = (float*)d_out;

    char* ws = (char*)d_ws;
    double*   moments4 = (double*)(ws);             // 0     .. 57344
    double*   res4     = (double*)(ws + 57344);     // 57344 .. 61440
    double*   scal64   = (double*)(ws + 61440);     // 61440 .. 63488
    unsigned* maxfg64  = (unsigned*)(ws + 63488);   // 63488 .. 63744
    float*    params   = (float*)(ws + 63744);      // 63744 .. 66816
    int*      valid    = (int*)(ws + 66816);        // 66816 .. 67328

    hipMemsetAsync(d_ws, 0, 67584, stream);

    moments_kernel<<<dim3(NPIX / 2048), dim3(256), 0, stream>>>(flow, masks, moments4);
    stencil_kernel<<<dim3(NPIX / 2048), dim3(256), 0, stream>>>(
        flow, masks, images, scal64, maxfg64);
    solve_kernel<<<dim3(1), dim3(128), 0, stream>>>(moments4, params, valid, out);
    pass2_kernel<<<dim3(NPIX / 4096), dim3(256), 0, stream>>>(
        flow, masks, params, res4);
    final_kernel<<<dim3(1), dim3(128), 0, stream>>>(
        moments4, res4, valid, scal64, maxfg64, out);
}